// Round 9
// baseline (448.427 us; speedup 1.0000x reference)
//
#include <hip/hip_runtime.h>

// LSTM: B=8192, T=512, IN=8, H=64, OUT=1
// R13 (on R12): micro-fixes from counter/issue-order audit.
//   - xlds diet: x16-MFMA A-weights are ALREADY zero for k in [8,16), so the
//     B-side zero tail was dead. XROW 24 -> 8 f16 (16B rows, aligned b128
//     staging writes); q>=2 bx reads overrun into neighbor rows by design
//     (finite garbage x zero weight = 0); 16-f16 zero pad guards array end.
//     LDS 29.2KB -> ~13KB; zero-tail init deleted.
//   - staging pack (tt==0) + global prefetch (tt==1) moved AFTER the h
//     writeback: off the act's in-order issue path, into the barrier shadow.
//   - h writeback split: half2 write right after each act_pair (tail cut).
// R12: merged rcps (kept: demand slightly lower; measured neutral -> trans
//   is ~8cyc/wave, VALU demand is spread, not trans-dominated).
// R11/R7 (reverted): 1 block/CU topologies = -28..31%. Grid=512 pins
//   2 blocks/CU; 2 waves/SIMD is the structural max (3 experiments).
// R10 (reverted): soft-barrier + stagger null.
// R9: chunk-top barrier removed; bx chunk-preloaded; setprio. 334.0 us.
// R8: transposed MFMA (A=weights,B=h/x); packed writeback; x16 x-term. 339.6.
// R5: scaled-domain chat (5 exp2 + 2 rcp / element).
// MFMA layouts (m89/m91/m120 verified):
//   A[m=lane&15][k=(lane>>4)*8+j] (x32) / [k=(lane>>4)*4+j] (x16),
//   B[k][n=lane&15], C/D: col=lane&15, row=(lane>>4)*4+reg.

typedef _Float16 f16_t;
typedef _Float16 half8 __attribute__((ext_vector_type(8)));
typedef _Float16 half4 __attribute__((ext_vector_type(4)));
typedef __fp16 fp16x2 __attribute__((ext_vector_type(2)));
typedef float floatx2 __attribute__((ext_vector_type(2)));
typedef float floatx4 __attribute__((ext_vector_type(4)));

#define Bn 8192
#define Tn 512
#define INn 8
#define Hn 64
#define BT 16
#define CHUNK 16
#define NCHUNK (Tn / CHUNK)
#define HSTRIDE 72   // f16; row = 144B: b128 reads 16B-aligned
#define XROW 8       // f16 per batch row: 8 real only (16B, aligned)
#define XSZ (2 * CHUNK * BT * XROW)   // + 16 pad f16

__device__ __forceinline__ floatx2 act_pair(float zi0, float zi1,
                                            float zf0, float zf1,
                                            float zg0, float zg1,
                                            float zo0, float zo1,
                                            floatx2& chat) {
  const floatx2 one  = {1.f, 1.f};
  const float  K2   = 2.8853900817779268f;  // 2*log2(e)
  const floatx2 K2v  = {K2, K2};
  const floatx2 mK2v = {-K2, -K2};
  const floatx2 clmp = {126.f, 126.f};
  floatx2 A = {__builtin_amdgcn_exp2f(zi0), __builtin_amdgcn_exp2f(zi1)};
  floatx2 G = {__builtin_amdgcn_exp2f(zg0), __builtin_amdgcn_exp2f(zg1)};
  floatx2 F = {__builtin_amdgcn_exp2f(zf0), __builtin_amdgcn_exp2f(zf1)};
  floatx2 O = {__builtin_amdgcn_exp2f(zo0), __builtin_amdgcn_exp2f(zo1)};
  floatx2 PA  = A + one;
  floatx2 PG  = G + one;
  floatx2 PF  = F + one;
  floatx2 PAG = PA * PG;
  floatx2 num = __builtin_elementwise_fma(G, K2v, mK2v) * PF;  // K(G-1)(1+F)
  floatx2 s   = __builtin_elementwise_fma(chat, PAG, num);
  floatx2 P3  = PF * PAG;
  // merged reciprocal: 1 rcp + 3 muls instead of 2 rcps
  {
    const float r3 = __builtin_amdgcn_rcpf(P3.x * P3.y);
    const floatx2 r3v = {r3, r3};
    const floatx2 P3s = {P3.y, P3.x};
    chat = __builtin_elementwise_min(s * (r3v * P3s), clmp);
  }
  floatx2 C2 = {__builtin_amdgcn_exp2f(chat.x), __builtin_amdgcn_exp2f(chat.y)};
  floatx2 P4 = (O + one) * (C2 + one);
  {
    const float r4 = __builtin_amdgcn_rcpf(P4.x * P4.y);
    const floatx2 r4v = {r4, r4};
    const floatx2 P4s = {P4.y, P4.x};
    return (C2 - one) * (r4v * P4s);  // h = o * tanh(c)
  }
}

__global__ __launch_bounds__(256, 2)
void lstm_fused(const float* __restrict__ xg,
                const float* __restrict__ W_ih,
                const float* __restrict__ W_hh,
                const float* __restrict__ b_ih,
                const float* __restrict__ b_hh,
                const float* __restrict__ W_fc,
                const float* __restrict__ b_fc,
                float* __restrict__ out)
{
  __shared__ alignas(16) f16_t hbuf[2][BT][HSTRIDE];   // [par][batch][unit]
  __shared__ alignas(16) f16_t xarena[XSZ + 16];       // [(par*CHUNK+tt)*BT+row]*XROW + 16 pad

  const int tid   = threadIdx.x;
  const int wv    = tid >> 6;     // wave 0..3 -> hidden units 16w..16w+15
  const int lane  = tid & 63;
  const int n     = lane & 15;    // A-row (unit) / B-col (batch) / D-col
  const int q     = lane >> 4;    // quad
  const int bbase = blockIdx.x * BT;

  const float LOG2E = 1.4426950408889634f;

  // ---- weight A-fragments, pre-scaled, resident in VGPRs.
  half8 bf[4][2];
  half4 bfx[4];
  #pragma unroll
  for (int g = 0; g < 4; ++g) {
    const float sc = (g == 2) ? (2.f * LOG2E) : (-LOG2E);
    const int C = g * 64 + wv * 16 + n;   // global gate-unit row
    #pragma unroll
    for (int c = 0; c < 2; ++c) {
      half8 v;
      #pragma unroll
      for (int j = 0; j < 8; ++j) {
        const int k = c * 32 + q * 8 + j;          // < 64 always
        v[j] = (f16_t)(W_hh[C * Hn + k] * sc);
      }
      bf[g][c] = v;
    }
    half4 vx;
    #pragma unroll
    for (int j = 0; j < 4; ++j) {
      const int k = q * 4 + j;                     // [0,16)
      vx[j] = (f16_t)((k < INn) ? (W_ih[C * INn + k] * sc) : 0.f);
    }
    bfx[g] = vx;   // zero for k>=8: annihilates any garbage B at k>=8
  }

  // ---- scaled biases -> persistent MFMA C-operand registers.
  const int u0 = wv * 16 + q * 4;   // lane covers units u0..u0+3
  floatx4 bi, bfv, bg, bo;
  #pragma unroll
  for (int r = 0; r < 4; ++r) {
    const int uu = u0 + r;
    bi[r]  = -(b_ih[uu]        + b_hh[uu])        * LOG2E;
    bfv[r] = -(b_ih[64 + uu]   + b_hh[64 + uu])   * LOG2E;
    bg[r]  =  (b_ih[128 + uu]  + b_hh[128 + uu])  * (2.f * LOG2E);
    bo[r]  = -(b_ih[192 + uu]  + b_hh[192 + uu])  * LOG2E;
  }

  // ---- x staging assignment: lane -> (row, tt); 16-lane groups coalesce 512B
  const int row_s = tid >> 4;   // 0..15 batch row
  const int tt_s  = tid & 15;   // 0..15 timestep within chunk
  const float* xps = xg + ((size_t)(bbase + row_s) * Tn + tt_s) * INn;

  // ---- one-time LDS init: hbuf[0] = 0; arena pad = 0; chunk 0 -> parity 0
  for (int i = tid; i < BT * HSTRIDE; i += 256) ((f16_t*)hbuf[0])[i] = (f16_t)0.f;
  if (tid < 16) xarena[XSZ + tid] = (f16_t)0.f;
  {
    float4 a  = *(const float4*)(xps);
    float4 b2 = *(const float4*)(xps + 4);
    union { half8 v; fp16x2 h2[4]; } P;
    P.h2[0] = __builtin_amdgcn_cvt_pkrtz(a.x, a.y);
    P.h2[1] = __builtin_amdgcn_cvt_pkrtz(a.z, a.w);
    P.h2[2] = __builtin_amdgcn_cvt_pkrtz(b2.x, b2.y);
    P.h2[3] = __builtin_amdgcn_cvt_pkrtz(b2.z, b2.w);
    *(half8*)&xarena[(tt_s * BT + row_s) * XROW] = P.v;
  }
  // preload chunk 1 into registers (written to LDS at ch=0, tt=0)
  float4 pa  = *(const float4*)(xps + CHUNK * INn);
  float4 pb2 = *(const float4*)(xps + CHUNK * INn + 4);

  __syncthreads();  // hbuf zero + pad + chunk 0 visible

  floatx2 chat01 = {0.f, 0.f};  // scaled cell state, units u0+{0,1}
  floatx2 chat23 = {0.f, 0.f};  // units u0+{2,3}

  for (int ch = 0; ch < NCHUNK; ++ch) {
    // ---- chunk-top (no barrier): preload this chunk's 16 x fragments.
    // xarena parity (ch&1) published by prev chunk's tt=15 barrier (ch=0: init).
    // q>=2 reads overrun into the next row: finite garbage x zero A-weight.
    half4 bx[CHUNK];
    #pragma unroll
    for (int t = 0; t < CHUNK; ++t)
      bx[t] = *(const half4*)&xarena[(((ch & 1) * CHUNK + t) * BT + n) * XROW + q * 4];

    #pragma unroll
    for (int tt = 0; tt < CHUNK; ++tt) {
      const int p  = tt & 1;
      const int pn = p ^ 1;

      // post-barrier critical chain: h fragments only
      const half8 b0 = *(const half8*)&hbuf[p][n][q * 8];
      const half8 b1 = *(const half8*)&hbuf[p][n][32 + q * 8];

      __builtin_amdgcn_s_setprio(1);
      // D = W * (h|x) + bias; bias regs as first-MFMA C operand
      floatx4 ai = __builtin_amdgcn_mfma_f32_16x16x32_f16(bf[0][0], b0, bi,  0, 0, 0);
      floatx4 af = __builtin_amdgcn_mfma_f32_16x16x32_f16(bf[1][0], b0, bfv, 0, 0, 0);
      floatx4 ag = __builtin_amdgcn_mfma_f32_16x16x32_f16(bf[2][0], b0, bg,  0, 0, 0);
      floatx4 ao = __builtin_amdgcn_mfma_f32_16x16x32_f16(bf[3][0], b0, bo,  0, 0, 0);
      ai = __builtin_amdgcn_mfma_f32_16x16x32_f16(bf[0][1], b1, ai, 0, 0, 0);
      af = __builtin_amdgcn_mfma_f32_16x16x32_f16(bf[1][1], b1, af, 0, 0, 0);
      ag = __builtin_amdgcn_mfma_f32_16x16x32_f16(bf[2][1], b1, ag, 0, 0, 0);
      ao = __builtin_amdgcn_mfma_f32_16x16x32_f16(bf[3][1], b1, ao, 0, 0, 0);
      ai = __builtin_amdgcn_mfma_f32_16x16x16f16(bfx[0], bx[tt], ai, 0, 0, 0);
      af = __builtin_amdgcn_mfma_f32_16x16x16f16(bfx[1], bx[tt], af, 0, 0, 0);
      ag = __builtin_amdgcn_mfma_f32_16x16x16f16(bfx[2], bx[tt], ag, 0, 0, 0);
      ao = __builtin_amdgcn_mfma_f32_16x16x16f16(bfx[3], bx[tt], ao, 0, 0, 0);
      __builtin_amdgcn_s_setprio(0);

      // activations: lane's 4 elements = units u0+0..3, batch n.
      // Write each half-pair as soon as ready (tail cut).
      {
        const floatx2 h01 = act_pair(ai[0], ai[1], af[0], af[1],
                                     ag[0], ag[1], ao[0], ao[1], chat01);
        *(fp16x2*)&hbuf[pn][n][u0] = __builtin_amdgcn_cvt_pkrtz(h01.x, h01.y);
      }
      {
        const floatx2 h23 = act_pair(ai[2], ai[3], af[2], af[3],
                                     ag[2], ag[3], ao[2], ao[3], chat23);
        *(fp16x2*)&hbuf[pn][n][u0 + 2] = __builtin_amdgcn_cvt_pkrtz(h23.x, h23.y);
      }

      // off-issue-path staging, in the barrier shadow (after act):
      if (tt == 0) {
        // publish chunk ch+1 into the opposite parity; the step barrier
        // publishes it (that parity's last reads: chunk ch-1 preload burst).
        union { half8 v; fp16x2 h2[4]; } P;
        P.h2[0] = __builtin_amdgcn_cvt_pkrtz(pa.x, pa.y);
        P.h2[1] = __builtin_amdgcn_cvt_pkrtz(pa.z, pa.w);
        P.h2[2] = __builtin_amdgcn_cvt_pkrtz(pb2.x, pb2.y);
        P.h2[3] = __builtin_amdgcn_cvt_pkrtz(pb2.z, pb2.w);
        *(half8*)&xarena[((((ch + 1) & 1) * CHUNK + tt_s) * BT + row_s) * XROW] = P.v;
      }
      if (tt == 1) {
        // reissue global prefetch (chunk ch+2, wrapped); consumed 15 steps on
        const int chn = (ch + 2 < NCHUNK) ? (ch + 2) : (ch + 2 - NCHUNK);
        pa  = *(const float4*)(xps + (size_t)chn * CHUNK * INn);
        pb2 = *(const float4*)(xps + (size_t)chn * CHUNK * INn + 4);
      }

      __syncthreads();
    }
  }

  // ---- epilogue: out[b] = h_T[b,:] . W_fc + b_fc   (h_T is in hbuf[0])
  if (tid < 64) {
    const int b = lane & 15;
    const int part = lane >> 4;
    float s = 0.f;
    #pragma unroll
    for (int k = 0; k < 16; ++k) {
      const int uu = part * 16 + k;
      s = __builtin_fmaf((float)hbuf[0][b][uu], W_fc[uu], s);
    }
    s += __shfl_down(s, 32);
    s += __shfl_down(s, 16);
    if (lane < 16) out[bbase + b] = s + b_fc[0];
  }
}

extern "C" void kernel_launch(void* const* d_in, const int* in_sizes, int n_in,
                              void* d_out, int out_size, void* d_ws, size_t ws_size,
                              hipStream_t stream) {
  const float* x    = (const float*)d_in[0];
  const float* W_ih = (const float*)d_in[1];
  const float* W_hh = (const float*)d_in[2];
  const float* b_ih = (const float*)d_in[3];
  const float* b_hh = (const float*)d_in[4];
  const float* W_fc = (const float*)d_in[5];
  const float* b_fc = (const float*)d_in[6];
  float* out = (float*)d_out;
  dim3 grid(Bn / BT), block(256);
  hipLaunchKernelGGL(lstm_fused, grid, block, 0, stream,
                     x, W_ih, W_hh, b_ih, b_hh, W_fc, b_fc, out);
}

// Round 10
// 445.603 us; speedup vs baseline: 1.0063x; 1.0063x over previous
//
#include <hip/hip_runtime.h>

// LSTM: B=8192, T=512, IN=8, H=64, OUT=1
// R14 (on R12): 8-wave blocks -> 4 waves/SIMD, same total work.
//   Counters pinned at MfmaUtil+VALUBusy ~83% for 9 rounds: MFMA windows
//   never overlap VALU with only 2 waves/SIMD, and every within-topology
//   scheduling fix failed. This round adds issue streams: 512-thread
//   blocks (8 waves x 8 units each), grid 512, 2 blocks/CU = 4 waves/SIMD.
//   Key packing: A-tile rows gate-interleaved (row r = gate (r&3) of unit
//   (r>>2)) so each lane's D floatx4 = {i,f,g,o} of ONE unit -> one
//   act_pair per lane, no cross-lane traffic. Per wave: 6 MFMAs (two
//   independent 3-chains) + 1 act_pair + 2 b16 h-writes.
// R13 (reverted): micro-fixes bundle regressed -15us.
// R12: merged rcps (kept). 336.7 us ~= R9 334.0 (noise).
// R11/R7 (reverted): 1 wave/SIMD topologies -28..31%.
// R10 (reverted): soft-barrier + stagger null.
// R9: chunk-top barrier removed; bx chunk-preloaded; setprio. 334.0 us.
// R8: transposed MFMA (A=weights, B=h/x); x16 x-term. 339.6 us.
// R5: scaled-domain chat (5 exp2 + 2 rcp / element).
// MFMA layouts (m89/m91/m120 verified):
//   A[m=lane&15][k=(lane>>4)*8+j] (x32) / [k=(lane>>4)*4+j] (x16),
//   B[k][n=lane&15], C/D: col=lane&15, row=(lane>>4)*4+reg.

typedef _Float16 f16_t;
typedef _Float16 half8 __attribute__((ext_vector_type(8)));
typedef _Float16 half4 __attribute__((ext_vector_type(4)));
typedef __fp16 fp16x2 __attribute__((ext_vector_type(2)));
typedef float floatx2 __attribute__((ext_vector_type(2)));
typedef float floatx4 __attribute__((ext_vector_type(4)));

#define Bn 8192
#define Tn 512
#define INn 8
#define Hn 64
#define BT 16
#define NW 8          // waves per block
#define NTHR (NW * 64)
#define CHUNK 16
#define NCHUNK (Tn / CHUNK)
#define HSTRIDE 72    // f16; row = 144B: b128 reads 16B-aligned, 2-way banks
#define XROW 24       // f16 per batch row: 8 real + 16 zero; 48B

__device__ __forceinline__ floatx2 act_pair(float zi0, float zi1,
                                            float zf0, float zf1,
                                            float zg0, float zg1,
                                            float zo0, float zo1,
                                            floatx2& chat) {
  const floatx2 one  = {1.f, 1.f};
  const float  K2   = 2.8853900817779268f;  // 2*log2(e)
  const floatx2 K2v  = {K2, K2};
  const floatx2 mK2v = {-K2, -K2};
  const floatx2 clmp = {126.f, 126.f};
  floatx2 A = {__builtin_amdgcn_exp2f(zi0), __builtin_amdgcn_exp2f(zi1)};
  floatx2 G = {__builtin_amdgcn_exp2f(zg0), __builtin_amdgcn_exp2f(zg1)};
  floatx2 F = {__builtin_amdgcn_exp2f(zf0), __builtin_amdgcn_exp2f(zf1)};
  floatx2 O = {__builtin_amdgcn_exp2f(zo0), __builtin_amdgcn_exp2f(zo1)};
  floatx2 PA  = A + one;
  floatx2 PG  = G + one;
  floatx2 PF  = F + one;
  floatx2 PAG = PA * PG;
  floatx2 num = __builtin_elementwise_fma(G, K2v, mK2v) * PF;  // K(G-1)(1+F)
  floatx2 s   = __builtin_elementwise_fma(chat, PAG, num);
  floatx2 P3  = PF * PAG;
  // merged reciprocal: 1 rcp + 3 muls instead of 2 rcps
  {
    const float r3 = __builtin_amdgcn_rcpf(P3.x * P3.y);
    const floatx2 r3v = {r3, r3};
    const floatx2 P3s = {P3.y, P3.x};
    chat = __builtin_elementwise_min(s * (r3v * P3s), clmp);
  }
  floatx2 C2 = {__builtin_amdgcn_exp2f(chat.x), __builtin_amdgcn_exp2f(chat.y)};
  floatx2 P4 = (O + one) * (C2 + one);
  {
    const float r4 = __builtin_amdgcn_rcpf(P4.x * P4.y);
    const floatx2 r4v = {r4, r4};
    const floatx2 P4s = {P4.y, P4.x};
    return (C2 - one) * (r4v * P4s);  // h = o * tanh(c)
  }
}

__global__ __launch_bounds__(NTHR, 4)
void lstm_fused(const float* __restrict__ xg,
                const float* __restrict__ W_ih,
                const float* __restrict__ W_hh,
                const float* __restrict__ b_ih,
                const float* __restrict__ b_hh,
                const float* __restrict__ W_fc,
                const float* __restrict__ b_fc,
                float* __restrict__ out)
{
  __shared__ alignas(16) f16_t hbuf[2][BT][HSTRIDE];      // [par][batch][unit]
  __shared__ alignas(16) f16_t xlds[2][CHUNK][BT][XROW];  // [par][tt][batch][feat]

  const int tid   = threadIdx.x;
  const int wv    = tid >> 6;     // wave 0..7 -> hidden units 8w..8w+7
  const int lane  = tid & 63;
  const int n     = lane & 15;    // A-row index / B-col (batch) / D-col
  const int q     = lane >> 4;    // quad
  const int bbase = blockIdx.x * BT;

  const float LOG2E = 1.4426950408889634f;

  // ---- weight A-fragments, gate-interleaved tiles, resident in VGPRs.
  // Tile T (T=0,1): row r = gate (r&3) of unit 8*wv + 4*T + (r>>2).
  // A layout: lane supplies row m=n, cols k=(x32: c*32+q*8+j | x16: q*4+j).
  half8 bf[2][2];   // [tile][kchunk]
  half4 bfx[2];     // [tile]
  #pragma unroll
  for (int T = 0; T < 2; ++T) {
    const int gate = n & 3;
    const int unit = 8 * wv + 4 * T + (n >> 2);
    const float sc = (gate == 2) ? (2.f * LOG2E) : (-LOG2E);
    const int C = gate * 64 + unit;   // global gate-unit row
    #pragma unroll
    for (int c = 0; c < 2; ++c) {
      half8 v;
      #pragma unroll
      for (int j = 0; j < 8; ++j) {
        const int k = c * 32 + q * 8 + j;          // < 64 always
        v[j] = (f16_t)(W_hh[C * Hn + k] * sc);
      }
      bf[T][c] = v;
    }
    half4 vx;
    #pragma unroll
    for (int j = 0; j < 4; ++j) {
      const int k = q * 4 + j;                     // [0,16)
      vx[j] = (f16_t)((k < INn) ? (W_ih[C * INn + k] * sc) : 0.f);
    }
    bfx[T] = vx;
  }

  // ---- scaled biases -> persistent MFMA C-operand registers.
  // D rows q*4+reg = gate reg of unit uT = 8*wv + 4*T + q.
  floatx4 bias[2];
  #pragma unroll
  for (int T = 0; T < 2; ++T) {
    const int uT = 8 * wv + 4 * T + q;
    bias[T][0] = -(b_ih[uT]        + b_hh[uT])        * LOG2E;
    bias[T][1] = -(b_ih[64 + uT]   + b_hh[64 + uT])   * LOG2E;
    bias[T][2] =  (b_ih[128 + uT]  + b_hh[128 + uT])  * (2.f * LOG2E);
    bias[T][3] = -(b_ih[192 + uT]  + b_hh[192 + uT])  * LOG2E;
  }
  const int uA = 8 * wv + q;       // unit of acc tile 0
  const int uB = 8 * wv + 4 + q;   // unit of acc tile 1

  // ---- x staging assignment (first 4 waves): lane -> (row, tt)
  const int row_s = (tid >> 4) & 15;   // 0..15 batch row
  const int tt_s  = tid & 15;          // 0..15 timestep within chunk
  const float* xps = xg + ((size_t)(bbase + row_s) * Tn + tt_s) * INn;

  // ---- one-time LDS init (all writes disjoint -> single barrier):
  //   hbuf[0] = 0; x k-tails [8..24) = 0 (both parities); chunk 0 -> xlds[0]
  for (int i = tid; i < BT * HSTRIDE; i += NTHR) ((f16_t*)hbuf[0])[i] = (f16_t)0.f;
  {
    const half8 z = {};
    for (int r = tid; r < 2 * CHUNK * BT; r += NTHR) {
      f16_t* base = &xlds[r >> 8][(r >> 4) & 15][r & 15][0];
      *(half8*)(base + 8)  = z;
      *(half8*)(base + 16) = z;
    }
  }
  float4 pa = {}, pb2 = {};
  if (tid < 256) {
    float4 a  = *(const float4*)(xps);
    float4 b2 = *(const float4*)(xps + 4);
    union { half8 v; fp16x2 h2[4]; } P;
    P.h2[0] = __builtin_amdgcn_cvt_pkrtz(a.x, a.y);
    P.h2[1] = __builtin_amdgcn_cvt_pkrtz(a.z, a.w);
    P.h2[2] = __builtin_amdgcn_cvt_pkrtz(b2.x, b2.y);
    P.h2[3] = __builtin_amdgcn_cvt_pkrtz(b2.z, b2.w);
    *(half8*)&xlds[0][tt_s][row_s][0] = P.v;
    // preload chunk 1 into registers (written to LDS at ch=0, tt=0)
    pa  = *(const float4*)(xps + CHUNK * INn);
    pb2 = *(const float4*)(xps + CHUNK * INn + 4);
  }

  __syncthreads();  // hbuf zero + x tails + chunk 0 visible

  floatx2 chat = {0.f, 0.f};  // scaled cell state, units (uA, uB), batch n

  for (int ch = 0; ch < NCHUNK; ++ch) {
    // ---- chunk-top (no barrier): preload this chunk's 16 x fragments.
    // xlds[ch&1] was published by prev chunk's tt=15 barrier (ch=0: init).
    half4 bx[CHUNK];
    #pragma unroll
    for (int t = 0; t < CHUNK; ++t)
      bx[t] = *(const half4*)&xlds[ch & 1][t][n][q * 4];

    #pragma unroll
    for (int tt = 0; tt < CHUNK; ++tt) {
      const int p  = tt & 1;
      const int pn = p ^ 1;

      // post-barrier critical chain: h fragments only (shared by all waves)
      const half8 b0 = *(const half8*)&hbuf[p][n][q * 8];
      const half8 b1 = *(const half8*)&hbuf[p][n][32 + q * 8];

      __builtin_amdgcn_s_setprio(1);
      // two independent 3-chains; bias regs as first-MFMA C operand
      floatx4 a1 = __builtin_amdgcn_mfma_f32_16x16x32_f16(bf[0][0], b0, bias[0], 0, 0, 0);
      floatx4 a2 = __builtin_amdgcn_mfma_f32_16x16x32_f16(bf[1][0], b0, bias[1], 0, 0, 0);
      a1 = __builtin_amdgcn_mfma_f32_16x16x32_f16(bf[0][1], b1, a1, 0, 0, 0);
      a2 = __builtin_amdgcn_mfma_f32_16x16x32_f16(bf[1][1], b1, a2, 0, 0, 0);
      a1 = __builtin_amdgcn_mfma_f32_16x16x16f16(bfx[0], bx[tt], a1, 0, 0, 0);
      a2 = __builtin_amdgcn_mfma_f32_16x16x16f16(bfx[1], bx[tt], a2, 0, 0, 0);
      __builtin_amdgcn_s_setprio(0);

      // off-critical-path staging (first 4 waves), hidden under MFMA/act:
      if (tt == 0 && tid < 256) {
        union { half8 v; fp16x2 h2[4]; } P;
        P.h2[0] = __builtin_amdgcn_cvt_pkrtz(pa.x, pa.y);
        P.h2[1] = __builtin_amdgcn_cvt_pkrtz(pa.z, pa.w);
        P.h2[2] = __builtin_amdgcn_cvt_pkrtz(pb2.x, pb2.y);
        P.h2[3] = __builtin_amdgcn_cvt_pkrtz(pb2.z, pb2.w);
        *(half8*)&xlds[(ch + 1) & 1][tt_s][row_s][0] = P.v;
      }
      if (tt == 1 && tid < 256) {
        const int chn = (ch + 2 < NCHUNK) ? (ch + 2) : (ch + 2 - NCHUNK);
        pa  = *(const float4*)(xps + (size_t)chn * CHUNK * INn);
        pb2 = *(const float4*)(xps + (size_t)chn * CHUNK * INn + 4);
      }

      // act: lane's a1/a2 = {i,f,g,o} of units (uA,uB), batch n -> one pair
      const floatx2 h = act_pair(a1[0], a2[0], a1[1], a2[1],
                                 a1[2], a2[2], a1[3], a2[3], chat);
      hbuf[pn][n][uA] = (f16_t)h.x;
      hbuf[pn][n][uB] = (f16_t)h.y;

      __syncthreads();
    }
  }

  // ---- epilogue: out[b] = h_T[b,:] . W_fc + b_fc   (h_T is in hbuf[0])
  if (tid < 64) {
    const int b = lane & 15;
    const int part = lane >> 4;
    float s = 0.f;
    #pragma unroll
    for (int k = 0; k < 16; ++k) {
      const int uu = part * 16 + k;
      s = __builtin_fmaf((float)hbuf[0][b][uu], W_fc[uu], s);
    }
    s += __shfl_down(s, 32);
    s += __shfl_down(s, 16);
    if (lane < 16) out[bbase + b] = s + b_fc[0];
  }
}

extern "C" void kernel_launch(void* const* d_in, const int* in_sizes, int n_in,
                              void* d_out, int out_size, void* d_ws, size_t ws_size,
                              hipStream_t stream) {
  const float* x    = (const float*)d_in[0];
  const float* W_ih = (const float*)d_in[1];
  const float* W_hh = (const float*)d_in[2];
  const float* b_ih = (const float*)d_in[3];
  const float* b_hh = (const float*)d_in[4];
  const float* W_fc = (const float*)d_in[5];
  const float* b_fc = (const float*)d_in[6];
  float* out = (float*)d_out;
  dim3 grid(Bn / BT), block(NTHR);
  hipLaunchKernelGGL(lstm_fused, grid, block, 0, stream,
                     x, W_ih, W_hh, b_ih, b_hh, W_fc, b_fc, out);
}

// Round 11
// 436.848 us; speedup vs baseline: 1.0265x; 1.0200x over previous
//
#include <hip/hip_runtime.h>

// LSTM: B=8192, T=512, IN=8, H=64, OUT=1
// R15 (on R12): x-MFMA hoisted off the post-barrier critical chain.
//   Demand audit (R14): trans 96us + VALU 43us + MFMA 85us + HBM 11us all
//   << 334us, and 4-waves/SIMD (R14) left util unchanged => per-step
//   LATENCY-bound: 512 x ~780cyc block chain {ds_read h -> 3-MFMA chain ->
//   act chain -> write -> barrier}. This round: the x16 x-term MFMAs (no h
//   dependency) move to the PREVIOUS step's pre-barrier shadow (MFMA pipe
//   idle during act), seeded with bias; they become the C-operand of the
//   h-chain. Post-barrier chain = ds_read -> 2 MFMAs. tt==15 reads the
//   next chunk's x fragment from LDS (published 15 barriers earlier).
// R14 (reverted): 4 waves/SIMD -> identical util (phase-locked barriers);
//   barrier-group count pinned at 2/CU by grid=512.
// R13 (reverted): micro-fix bundle -15us.
// R12: merged rcps (kept). 336.7 us ~= R9 334.0 (noise).
// R11/R7 (reverted): 1 wave/SIMD topologies -28..31%.
// R10 (reverted): soft-barrier + stagger null.
// R9: chunk-top barrier removed; bx chunk-preloaded; setprio. 334.0 us.
// R8: transposed MFMA (A=weights, B=h/x); x16 x-term. 339.6 us.
// R5: scaled-domain chat (5 exp2 + 2 rcp / element).
// MFMA layouts (m89/m91/m120 verified):
//   A[m=lane&15][k=(lane>>4)*8+j] (x32) / [k=(lane>>4)*4+j] (x16),
//   B[k][n=lane&15], C/D: col=lane&15, row=(lane>>4)*4+reg.

typedef _Float16 f16_t;
typedef _Float16 half8 __attribute__((ext_vector_type(8)));
typedef _Float16 half4 __attribute__((ext_vector_type(4)));
typedef __fp16 fp16x2 __attribute__((ext_vector_type(2)));
typedef float floatx2 __attribute__((ext_vector_type(2)));
typedef float floatx4 __attribute__((ext_vector_type(4)));

#define Bn 8192
#define Tn 512
#define INn 8
#define Hn 64
#define BT 16
#define CHUNK 16
#define NCHUNK (Tn / CHUNK)
#define HSTRIDE 72   // f16; row = 144B: b128 reads 16B-aligned, 2-way banks
#define XROW 24      // f16 per batch row: 8 real + 16 zero; 48B

__device__ __forceinline__ floatx2 act_pair(float zi0, float zi1,
                                            float zf0, float zf1,
                                            float zg0, float zg1,
                                            float zo0, float zo1,
                                            floatx2& chat) {
  const floatx2 one  = {1.f, 1.f};
  const float  K2   = 2.8853900817779268f;  // 2*log2(e)
  const floatx2 K2v  = {K2, K2};
  const floatx2 mK2v = {-K2, -K2};
  const floatx2 clmp = {126.f, 126.f};
  floatx2 A = {__builtin_amdgcn_exp2f(zi0), __builtin_amdgcn_exp2f(zi1)};
  floatx2 G = {__builtin_amdgcn_exp2f(zg0), __builtin_amdgcn_exp2f(zg1)};
  floatx2 F = {__builtin_amdgcn_exp2f(zf0), __builtin_amdgcn_exp2f(zf1)};
  floatx2 O = {__builtin_amdgcn_exp2f(zo0), __builtin_amdgcn_exp2f(zo1)};
  floatx2 PA  = A + one;
  floatx2 PG  = G + one;
  floatx2 PF  = F + one;
  floatx2 PAG = PA * PG;
  floatx2 num = __builtin_elementwise_fma(G, K2v, mK2v) * PF;  // K(G-1)(1+F)
  floatx2 s   = __builtin_elementwise_fma(chat, PAG, num);
  floatx2 P3  = PF * PAG;
  // merged reciprocal: 1 rcp + 3 muls instead of 2 rcps
  {
    const float r3 = __builtin_amdgcn_rcpf(P3.x * P3.y);
    const floatx2 r3v = {r3, r3};
    const floatx2 P3s = {P3.y, P3.x};
    chat = __builtin_elementwise_min(s * (r3v * P3s), clmp);
  }
  floatx2 C2 = {__builtin_amdgcn_exp2f(chat.x), __builtin_amdgcn_exp2f(chat.y)};
  floatx2 P4 = (O + one) * (C2 + one);
  {
    const float r4 = __builtin_amdgcn_rcpf(P4.x * P4.y);
    const floatx2 r4v = {r4, r4};
    const floatx2 P4s = {P4.y, P4.x};
    return (C2 - one) * (r4v * P4s);  // h = o * tanh(c)
  }
}

__global__ __launch_bounds__(256, 2)
void lstm_fused(const float* __restrict__ xg,
                const float* __restrict__ W_ih,
                const float* __restrict__ W_hh,
                const float* __restrict__ b_ih,
                const float* __restrict__ b_hh,
                const float* __restrict__ W_fc,
                const float* __restrict__ b_fc,
                float* __restrict__ out)
{
  __shared__ alignas(16) f16_t hbuf[2][BT][HSTRIDE];      // [par][batch][unit]
  __shared__ alignas(16) f16_t xlds[2][CHUNK][BT][XROW];  // [par][tt][batch][feat]

  const int tid   = threadIdx.x;
  const int wv    = tid >> 6;     // wave 0..3 -> hidden units 16w..16w+15
  const int lane  = tid & 63;
  const int n     = lane & 15;    // A-row (unit) / B-col (batch) / D-col
  const int q     = lane >> 4;    // quad
  const int bbase = blockIdx.x * BT;

  const float LOG2E = 1.4426950408889634f;

  // ---- weight A-fragments, pre-scaled, resident in VGPRs.
  half8 bf[4][2];
  half4 bfx[4];
  #pragma unroll
  for (int g = 0; g < 4; ++g) {
    const float sc = (g == 2) ? (2.f * LOG2E) : (-LOG2E);
    const int C = g * 64 + wv * 16 + n;   // global gate-unit row
    #pragma unroll
    for (int c = 0; c < 2; ++c) {
      half8 v;
      #pragma unroll
      for (int j = 0; j < 8; ++j) {
        const int k = c * 32 + q * 8 + j;          // < 64 always
        v[j] = (f16_t)(W_hh[C * Hn + k] * sc);
      }
      bf[g][c] = v;
    }
    half4 vx;
    #pragma unroll
    for (int j = 0; j < 4; ++j) {
      const int k = q * 4 + j;                     // [0,16)
      vx[j] = (f16_t)((k < INn) ? (W_ih[C * INn + k] * sc) : 0.f);
    }
    bfx[g] = vx;
  }

  // ---- scaled biases -> persistent MFMA C-operand registers.
  const int u0 = wv * 16 + q * 4;   // lane covers units u0..u0+3
  floatx4 bi, bfv, bg, bo;
  #pragma unroll
  for (int r = 0; r < 4; ++r) {
    const int uu = u0 + r;
    bi[r]  = -(b_ih[uu]        + b_hh[uu])        * LOG2E;
    bfv[r] = -(b_ih[64 + uu]   + b_hh[64 + uu])   * LOG2E;
    bg[r]  =  (b_ih[128 + uu]  + b_hh[128 + uu])  * (2.f * LOG2E);
    bo[r]  = -(b_ih[192 + uu]  + b_hh[192 + uu])  * LOG2E;
  }

  // ---- x staging assignment: lane -> (row, tt); 16-lane groups coalesce 512B
  const int row_s = tid >> 4;   // 0..15 batch row
  const int tt_s  = tid & 15;   // 0..15 timestep within chunk
  const float* xps = xg + ((size_t)(bbase + row_s) * Tn + tt_s) * INn;

  // ---- one-time LDS init (all writes disjoint -> single barrier):
  //   hbuf[0] = 0; x k-tails [8..24) = 0 (both parities); chunk 0 -> xlds[0]
  for (int i = tid; i < BT * HSTRIDE; i += 256) ((f16_t*)hbuf[0])[i] = (f16_t)0.f;
  {
    const half8 z = {};
    #pragma unroll
    for (int r = tid; r < 2 * CHUNK * BT; r += 256) {
      f16_t* base = &xlds[r >> 8][(r >> 4) & 15][r & 15][0];
      *(half8*)(base + 8)  = z;
      *(half8*)(base + 16) = z;
    }
  }
  {
    float4 a  = *(const float4*)(xps);
    float4 b2 = *(const float4*)(xps + 4);
    union { half8 v; fp16x2 h2[4]; } P;
    P.h2[0] = __builtin_amdgcn_cvt_pkrtz(a.x, a.y);
    P.h2[1] = __builtin_amdgcn_cvt_pkrtz(a.z, a.w);
    P.h2[2] = __builtin_amdgcn_cvt_pkrtz(b2.x, b2.y);
    P.h2[3] = __builtin_amdgcn_cvt_pkrtz(b2.z, b2.w);
    *(half8*)&xlds[0][tt_s][row_s][0] = P.v;
  }
  // preload chunk 1 into registers (written to LDS at ch=0, tt=0)
  float4 pa  = *(const float4*)(xps + CHUNK * INn);
  float4 pb2 = *(const float4*)(xps + CHUNK * INn + 4);

  __syncthreads();  // hbuf zero + x tails + chunk 0 visible

  floatx2 chat01 = {0.f, 0.f};  // scaled cell state, units u0+{0,1}
  floatx2 chat23 = {0.f, 0.f};  // units u0+{2,3}

  // ---- prologue: x-gate accumulators for (ch=0, tt=0), seeded with bias
  floatx4 xai, xaf, xag, xao;
  {
    const half4 bx0 = *(const half4*)&xlds[0][0][n][q * 4];
    xai = __builtin_amdgcn_mfma_f32_16x16x16f16(bfx[0], bx0, bi,  0, 0, 0);
    xaf = __builtin_amdgcn_mfma_f32_16x16x16f16(bfx[1], bx0, bfv, 0, 0, 0);
    xag = __builtin_amdgcn_mfma_f32_16x16x16f16(bfx[2], bx0, bg,  0, 0, 0);
    xao = __builtin_amdgcn_mfma_f32_16x16x16f16(bfx[3], bx0, bo,  0, 0, 0);
  }

  for (int ch = 0; ch < NCHUNK; ++ch) {
    // ---- chunk-top (no barrier): preload this chunk's 16 x fragments.
    // xlds[ch&1] was published by prev chunk's tt=15 barrier (ch=0: init).
    half4 bx[CHUNK];
    #pragma unroll
    for (int t = 0; t < CHUNK; ++t)
      bx[t] = *(const half4*)&xlds[ch & 1][t][n][q * 4];

    #pragma unroll
    for (int tt = 0; tt < CHUNK; ++tt) {
      const int p  = tt & 1;
      const int pn = p ^ 1;

      // post-barrier critical chain: h fragments -> 2-deep MFMA chain
      // (x-term already in xai..xao, computed last step's shadow)
      const half8 b0 = *(const half8*)&hbuf[p][n][q * 8];
      const half8 b1 = *(const half8*)&hbuf[p][n][32 + q * 8];

      __builtin_amdgcn_s_setprio(1);
      floatx4 ai = __builtin_amdgcn_mfma_f32_16x16x32_f16(bf[0][0], b0, xai, 0, 0, 0);
      floatx4 af = __builtin_amdgcn_mfma_f32_16x16x32_f16(bf[1][0], b0, xaf, 0, 0, 0);
      floatx4 ag = __builtin_amdgcn_mfma_f32_16x16x32_f16(bf[2][0], b0, xag, 0, 0, 0);
      floatx4 ao = __builtin_amdgcn_mfma_f32_16x16x32_f16(bf[3][0], b0, xao, 0, 0, 0);
      ai = __builtin_amdgcn_mfma_f32_16x16x32_f16(bf[0][1], b1, ai, 0, 0, 0);
      af = __builtin_amdgcn_mfma_f32_16x16x32_f16(bf[1][1], b1, af, 0, 0, 0);
      ag = __builtin_amdgcn_mfma_f32_16x16x32_f16(bf[2][1], b1, ag, 0, 0, 0);
      ao = __builtin_amdgcn_mfma_f32_16x16x32_f16(bf[3][1], b1, ao, 0, 0, 0);
      __builtin_amdgcn_s_setprio(0);

      // off-critical-path staging, hidden under MFMA/act latency:
      if (tt == 0) {
        // publish chunk ch+1 into the opposite parity; the step barrier
        // publishes it (that parity's last reads: chunk ch-1 preload burst).
        union { half8 v; fp16x2 h2[4]; } P;
        P.h2[0] = __builtin_amdgcn_cvt_pkrtz(pa.x, pa.y);
        P.h2[1] = __builtin_amdgcn_cvt_pkrtz(pa.z, pa.w);
        P.h2[2] = __builtin_amdgcn_cvt_pkrtz(pb2.x, pb2.y);
        P.h2[3] = __builtin_amdgcn_cvt_pkrtz(pb2.z, pb2.w);
        *(half8*)&xlds[(ch + 1) & 1][tt_s][row_s][0] = P.v;
      }
      if (tt == 1) {
        // reissue global prefetch (chunk ch+2, wrapped); consumed 15 steps on
        const int chn = (ch + 2 < NCHUNK) ? (ch + 2) : (ch + 2 - NCHUNK);
        pa  = *(const float4*)(xps + (size_t)chn * CHUNK * INn);
        pb2 = *(const float4*)(xps + (size_t)chn * CHUNK * INn + 4);
      }

      // activations: lane's 4 elements = units u0+0..3, batch n
      const floatx2 h01 = act_pair(ai[0], ai[1], af[0], af[1],
                                   ag[0], ag[1], ao[0], ao[1], chat01);
      const floatx2 h23 = act_pair(ai[2], ai[3], af[2], af[3],
                                   ag[2], ag[3], ao[2], ao[3], chat23);

      // packed writeback: 4 consecutive units of batch n -> one b64
      union { half4 v; fp16x2 h2[2]; } Wq;
      Wq.h2[0] = __builtin_amdgcn_cvt_pkrtz(h01.x, h01.y);
      Wq.h2[1] = __builtin_amdgcn_cvt_pkrtz(h23.x, h23.y);
      *(half4*)&hbuf[pn][n][u0] = Wq.v;

      // pre-barrier shadow: next step's x-gate accumulators (MFMA pipe is
      // idle during act). tt<15: bx from the chunk preload regs (no LDS
      // dep). tt==15: next chunk's [0] fragment from LDS (published at
      // this chunk's tt==0 barrier). Final iteration computes harmless
      // garbage (never consumed).
      {
        half4 bxn;
        if (tt < CHUNK - 1) {
          bxn = bx[tt + 1];
        } else {
          bxn = *(const half4*)&xlds[(ch + 1) & 1][0][n][q * 4];
        }
        xai = __builtin_amdgcn_mfma_f32_16x16x16f16(bfx[0], bxn, bi,  0, 0, 0);
        xaf = __builtin_amdgcn_mfma_f32_16x16x16f16(bfx[1], bxn, bfv, 0, 0, 0);
        xag = __builtin_amdgcn_mfma_f32_16x16x16f16(bfx[2], bxn, bg,  0, 0, 0);
        xao = __builtin_amdgcn_mfma_f32_16x16x16f16(bfx[3], bxn, bo,  0, 0, 0);
      }

      __syncthreads();
    }
  }

  // ---- epilogue: out[b] = h_T[b,:] . W_fc + b_fc   (h_T is in hbuf[0])
  if (tid < 64) {
    const int b = lane & 15;
    const int part = lane >> 4;
    float s = 0.f;
    #pragma unroll
    for (int k = 0; k < 16; ++k) {
      const int uu = part * 16 + k;
      s = __builtin_fmaf((float)hbuf[0][b][uu], W_fc[uu], s);
    }
    s += __shfl_down(s, 32);
    s += __shfl_down(s, 16);
    if (lane < 16) out[bbase + b] = s + b_fc[0];
  }
}

extern "C" void kernel_launch(void* const* d_in, const int* in_sizes, int n_in,
                              void* d_out, int out_size, void* d_ws, size_t ws_size,
                              hipStream_t stream) {
  const float* x    = (const float*)d_in[0];
  const float* W_ih = (const float*)d_in[1];
  const float* W_hh = (const float*)d_in[2];
  const float* b_ih = (const float*)d_in[3];
  const float* b_hh = (const float*)d_in[4];
  const float* W_fc = (const float*)d_in[5];
  const float* b_fc = (const float*)d_in[6];
  float* out = (float*)d_out;
  dim3 grid(Bn / BT), block(256);
  hipLaunchKernelGGL(lstm_fused, grid, block, 0, stream,
                     x, W_ih, W_hh, b_ih, b_hh, W_fc, b_fc, out);
}